// Round 26
// baseline (96.882 us; speedup 1.0000x reference)
//
#include <hip/hip_runtime.h>

typedef _Float16 f16x8 __attribute__((ext_vector_type(8)));
typedef __fp16 hf2 __attribute__((ext_vector_type(2)));
typedef float f32x4 __attribute__((ext_vector_type(4)));

#define MFMA32(A, B, C) __builtin_amdgcn_mfma_f32_16x16x32_f16(A, B, C, 0, 0, 0)
#define NEG_LOG2E (-1.4426950408889634f)

extern "C" __device__ float __ocml_native_exp2_f32(float);  // v_exp_f32: 2^x

struct P16 { f16x8 hi, lo; };

__device__ __forceinline__ f16x8 pk8(const float* v) {
  uint4 u;
  u.x = __builtin_bit_cast(unsigned, __builtin_amdgcn_cvt_pkrtz(v[0], v[1]));
  u.y = __builtin_bit_cast(unsigned, __builtin_amdgcn_cvt_pkrtz(v[2], v[3]));
  u.z = __builtin_bit_cast(unsigned, __builtin_amdgcn_cvt_pkrtz(v[4], v[5]));
  u.w = __builtin_bit_cast(unsigned, __builtin_amdgcn_cvt_pkrtz(v[6], v[7]));
  return __builtin_bit_cast(f16x8, u);
}
__device__ __forceinline__ P16 splitpk(const float* v) {
  unsigned uh[4], ul[4];
  float lo[8];
#pragma unroll
  for (int e = 0; e < 4; ++e) {
    const hf2 h = __builtin_amdgcn_cvt_pkrtz(v[2 * e], v[2 * e + 1]);
    uh[e] = __builtin_bit_cast(unsigned, h);
    lo[2 * e]     = v[2 * e]     - (float)h[0];
    lo[2 * e + 1] = v[2 * e + 1] - (float)h[1];
  }
#pragma unroll
  for (int e = 0; e < 4; ++e)
    ul[e] = __builtin_bit_cast(unsigned, __builtin_amdgcn_cvt_pkrtz(lo[2 * e], lo[2 * e + 1]));
  P16 p;
  p.hi = __builtin_bit_cast(f16x8, uint4{uh[0], uh[1], uh[2], uh[3]});
  p.lo = __builtin_bit_cast(f16x8, uint4{ul[0], ul[1], ul[2], ul[3]});
  return p;
}
__device__ __forceinline__ P16 splitpk16(float4 a, float4 b) {
  float v[8] = {a.x, a.y, a.z, a.w, b.x, b.y, b.z, b.w};
  return splitpk(v);
}
__device__ __forceinline__ float sigm2(float a) {
  return __builtin_amdgcn_rcpf(1.0f + __ocml_native_exp2_f32(a));
}

// prep: W' = -log2e * W -> f16 hi/lo fragment planes; scaled bias fragments.
__global__ void prep_wfrag(const float* __restrict__ W, const float* __restrict__ bias,
                           uint4* __restrict__ wf, f32x4* __restrict__ bf) {
  const int id = blockIdx.x * 256 + threadIdx.x;
  if (id < 2048) {
    const int T = id >> 6, l = id & 63, g = (l >> 4) & 3, li = l & 15;
    const int col = 16 * T + li;
    unsigned hi[8], lo[8];
#pragma unroll
    for (int e = 0; e < 8; ++e) {
      const int k = (e < 4) ? (4 * g + e) : (16 + 4 * g + (e - 4));
      const float v = (k < 28) ? W[col * 28 + k] * NEG_LOG2E : 0.0f;
      const _Float16 h = (_Float16)v;
      const _Float16 lw = (_Float16)(v - (float)h);
      hi[e] = __builtin_bit_cast(unsigned short, h);
      lo[e] = __builtin_bit_cast(unsigned short, lw);
    }
    uint4 uh, ul;
    uh.x = hi[0] | (hi[1] << 16); uh.y = hi[2] | (hi[3] << 16);
    uh.z = hi[4] | (hi[5] << 16); uh.w = hi[6] | (hi[7] << 16);
    ul.x = lo[0] | (lo[1] << 16); ul.y = lo[2] | (lo[3] << 16);
    ul.z = lo[4] | (lo[5] << 16); ul.w = lo[6] | (lo[7] << 16);
    wf[T * 64 + l] = uh;
    wf[(32 + T) * 64 + l] = ul;
  }
  if (id < 1024) {
    const int s = id >> 6, l = id & 63, g = (l >> 4) & 3;
    f32x4 b0, b1;
#pragma unroll
    for (int e = 0; e < 4; ++e) {
      b0[e] = bias[32 * s + 4 * g + e] * NEG_LOG2E;
      b1[e] = bias[32 * s + 16 + 4 * g + e] * NEG_LOG2E;
    }
    bf[id * 2 + 0] = b0;
    bf[id * 2 + 1] = b1;
  }
}

// ONE WAVE = TWO SAMPLES (R25 arithmetic, dual-chain ILP). Every W/bf/bias load
// is shared by both chains; the chains' MFMA/sigmoid/split/solve dependencies
// are independent -> program-order interleave fills each chain's latency
// bubbles. launch_bounds(256,2) -> 256-VGPR cap (structurally spill-proof).
// Grid 512 blocks x 4 waves x 2 samples. LDS 32KB/block. ZERO barriers.
__global__ __launch_bounds__(256, 2) void elm_kernel(
    const float* __restrict__ x, const uint4* __restrict__ wf,
    const f32x4* __restrict__ bf, const float* __restrict__ bias,
    float* __restrict__ Xout, float* __restrict__ Bout)
{
  __shared__ __align__(16) float sm[8192];   // 4 waves x 2 x 1024-word regions
  const int tid = threadIdx.x;
  const int w = tid >> 6, l = tid & 63, gl = l >> 4, li = l & 15;
  const int nA = blockIdx.x * 8 + 2 * w, nB = nA + 1;
  const int wbA = w * 2048, wbB = wbA + 1024;
  const float* xiA = x + (size_t)nA * 784;
  const float* xiB = x + (size_t)nB * 784;

  // ---- 1. x fragments for both samples ----
  const float4 z4 = {0, 0, 0, 0};
  const int r1 = (li < 12) ? 16 + li : 0;
  P16 XA0, XA1, XB0, XB1;
  {
    const float4 a0 = *reinterpret_cast<const float4*>(xiA + li * 28 + 4 * gl);
    const float4 b0 = (gl < 3) ? *reinterpret_cast<const float4*>(xiA + li * 28 + 16 + 4 * gl) : z4;
    float4 a1 = *reinterpret_cast<const float4*>(xiA + r1 * 28 + 4 * gl);
    float4 b1 = (gl < 3) ? *reinterpret_cast<const float4*>(xiA + r1 * 28 + 16 + 4 * gl) : z4;
    if (li >= 12) { a1 = z4; b1 = z4; }
    XA0 = splitpk16(a0, b0); XA1 = splitpk16(a1, b1);
  }
  {
    const float4 a0 = *reinterpret_cast<const float4*>(xiB + li * 28 + 4 * gl);
    const float4 b0 = (gl < 3) ? *reinterpret_cast<const float4*>(xiB + li * 28 + 16 + 4 * gl) : z4;
    float4 a1 = *reinterpret_cast<const float4*>(xiB + r1 * 28 + 4 * gl);
    float4 b1 = (gl < 3) ? *reinterpret_cast<const float4*>(xiB + r1 * 28 + 16 + 4 * gl) : z4;
    if (li >= 12) { a1 = z4; b1 = z4; }
    XB0 = splitpk16(a0, b0); XB1 = splitpk16(a1, b1);
  }

  // ---- 2. G phase: 16 chunks, W shared across both chains, prefetch depth 1 ----
  f32x4 dA00 = {0,0,0,0}, dA01 = {0,0,0,0}, dA11 = {0,0,0,0};
  f32x4 dB00 = {0,0,0,0}, dB01 = {0,0,0,0}, dB11 = {0,0,0,0};
  const int s_first = 4 * w;
  uint4 pW0h = wf[(2 * s_first) * 64 + l];
  uint4 pW0l = wf[(32 + 2 * s_first) * 64 + l];
  uint4 pW1h = wf[(2 * s_first + 1) * 64 + l];
  uint4 pW1l = wf[(32 + 2 * s_first + 1) * 64 + l];
#pragma unroll 1
  for (int ss = 0; ss < 16; ++ss) {
    const int s = (ss + 4 * w) & 15;
    const int sn = (ss + 1 + 4 * w) & 15;
    const f16x8 W0h = __builtin_bit_cast(f16x8, pW0h);
    const f16x8 W0l = __builtin_bit_cast(f16x8, pW0l);
    const f16x8 W1h = __builtin_bit_cast(f16x8, pW1h);
    const f16x8 W1l = __builtin_bit_cast(f16x8, pW1l);
    pW0h = wf[(2 * sn) * 64 + l];
    pW0l = wf[(32 + 2 * sn) * 64 + l];
    pW1h = wf[(2 * sn + 1) * 64 + l];
    pW1l = wf[(32 + 2 * sn + 1) * 64 + l];
    const f32x4 ba = bf[(s * 64 + l) * 2 + 0];  // shared by both chains
    const f32x4 bb = bf[(s * 64 + l) * 2 + 1];
    // chain A pre-activations
    f32x4 PA0 = ba, QA0 = bb, PA1 = ba, QA1 = bb;
    PA0 = MFMA32(W0h, XA0.hi, PA0); PA0 = MFMA32(W0h, XA0.lo, PA0); PA0 = MFMA32(W0l, XA0.hi, PA0);
    QA0 = MFMA32(W1h, XA0.hi, QA0); QA0 = MFMA32(W1h, XA0.lo, QA0); QA0 = MFMA32(W1l, XA0.hi, QA0);
    PA1 = MFMA32(W0h, XA1.hi, PA1); PA1 = MFMA32(W0h, XA1.lo, PA1); PA1 = MFMA32(W0l, XA1.hi, PA1);
    QA1 = MFMA32(W1h, XA1.hi, QA1); QA1 = MFMA32(W1h, XA1.lo, QA1); QA1 = MFMA32(W1l, XA1.hi, QA1);
    // chain B pre-activations (issue while A's MFMAs drain)
    f32x4 PB0 = ba, QB0 = bb, PB1 = ba, QB1 = bb;
    PB0 = MFMA32(W0h, XB0.hi, PB0); PB0 = MFMA32(W0h, XB0.lo, PB0); PB0 = MFMA32(W0l, XB0.hi, PB0);
    QB0 = MFMA32(W1h, XB0.hi, QB0); QB0 = MFMA32(W1h, XB0.lo, QB0); QB0 = MFMA32(W1l, XB0.hi, QB0);
    PB1 = MFMA32(W0h, XB1.hi, PB1); PB1 = MFMA32(W0h, XB1.lo, PB1); PB1 = MFMA32(W0l, XB1.hi, PB1);
    QB1 = MFMA32(W1h, XB1.hi, QB1); QB1 = MFMA32(W1h, XB1.lo, QB1); QB1 = MFMA32(W1l, XB1.hi, QB1);
    // chain A: sigmoid + split + G-accum
    {
      float f0[8], f1[8];
#pragma unroll
      for (int i = 0; i < 4; ++i) {
        f0[i] = sigm2(PA0[i]); f0[4 + i] = sigm2(QA0[i]);
        f1[i] = sigm2(PA1[i]); f1[4 + i] = sigm2(QA1[i]);
      }
      const P16 F0 = splitpk(f0);
      const P16 F1 = splitpk(f1);
      dA00 = MFMA32(F0.hi, F0.hi, dA00); dA00 = MFMA32(F0.hi, F0.lo, dA00); dA00 = MFMA32(F0.lo, F0.hi, dA00);
      dA01 = MFMA32(F0.hi, F1.hi, dA01); dA01 = MFMA32(F0.hi, F1.lo, dA01); dA01 = MFMA32(F0.lo, F1.hi, dA01);
      dA11 = MFMA32(F1.hi, F1.hi, dA11); dA11 = MFMA32(F1.hi, F1.lo, dA11); dA11 = MFMA32(F1.lo, F1.hi, dA11);
    }
    // chain B: sigmoid + split + G-accum
    {
      float f0[8], f1[8];
#pragma unroll
      for (int i = 0; i < 4; ++i) {
        f0[i] = sigm2(PB0[i]); f0[4 + i] = sigm2(QB0[i]);
        f1[i] = sigm2(PB1[i]); f1[4 + i] = sigm2(QB1[i]);
      }
      const P16 F0 = splitpk(f0);
      const P16 F1 = splitpk(f1);
      dB00 = MFMA32(F0.hi, F0.hi, dB00); dB00 = MFMA32(F0.hi, F0.lo, dB00); dB00 = MFMA32(F0.lo, F0.hi, dB00);
      dB01 = MFMA32(F0.hi, F1.hi, dB01); dB01 = MFMA32(F0.hi, F1.lo, dB01); dB01 = MFMA32(F0.lo, F1.hi, dB01);
      dB11 = MFMA32(F1.hi, F1.hi, dB11); dB11 = MFMA32(F1.hi, F1.lo, dB11); dB11 = MFMA32(F1.lo, F1.hi, dB11);
    }
  }

  // ---- 3. G fragments -> per-sample LDS regions ----
#pragma unroll
  for (int i = 0; i < 4; ++i) {
    const int ra = 4 * gl + i;
    sm[wbA + ra * 32 + li] = dA00[i];
    sm[wbA + ra * 32 + 16 + li] = dA01[i];
    sm[wbA + (16 + li) * 32 + ra] = dA01[i];
    sm[wbA + (16 + ra) * 32 + 16 + li] = dA11[i];
    sm[wbB + ra * 32 + li] = dB00[i];
    sm[wbB + ra * 32 + 16 + li] = dB01[i];
    sm[wbB + (16 + li) * 32 + ra] = dB01[i];
    sm[wbB + (16 + ra) * 32 + 16 + li] = dB11[i];
  }

  // ---- 4. X = x copies (overlap solve) + B-phase prefetch ----
  {
    const float4* xA4 = reinterpret_cast<const float4*>(xiA);
    const float4* xB4 = reinterpret_cast<const float4*>(xiB);
    float4* XA4 = reinterpret_cast<float4*>(Xout + (size_t)nA * 784);
    float4* XB4 = reinterpret_cast<float4*>(Xout + (size_t)nB * 784);
#pragma unroll
    for (int k = 0; k < 4; ++k) {
      const int idx = l + 64 * k;
      if (idx < 196) { XA4[idx] = xA4[idx]; XB4[idx] = xB4[idx]; }
    }
  }
  uint4 pWh = wf[((8 * w) & 31) * 64 + l];
  uint4 pWl = wf[(32 + ((8 * w) & 31)) * 64 + l];
  float pbv = bias[16 * ((8 * w) & 31) + li];

  // ---- 5. dual Gauss-Jordan solve (independent shfl chains interleave) ----
  {
    const int j = l;
    float colA[28], colB[28];
#pragma unroll
    for (int r = 0; r < 28; ++r) {
      float vA = 0.f, vB = 0.f;
      if (j < 28)      { vA = sm[wbA + r * 32 + j]; vB = sm[wbB + r * 32 + j]; }
      else if (j < 56) { vA = xiA[r * 28 + (j - 28)]; vB = xiB[r * 28 + (j - 28)]; }
      colA[r] = vA; colB[r] = vB;
    }
#pragma unroll
    for (int k = 0; k < 28; ++k) {
      const float pivA = __shfl(colA[k], k);
      const float pivB = __shfl(colB[k], k);
      const float invA = 1.0f / pivA;
      const float invB = 1.0f / pivB;
      colA[k] *= invA;
      colB[k] *= invB;
#pragma unroll
      for (int r2 = 0; r2 < 28; ++r2) {
        if (r2 == k) continue;
        const float mA = __shfl(colA[r2], k);
        const float mB = __shfl(colB[r2], k);
        colA[r2] -= mA * colA[k];
        colB[r2] -= mB * colB[k];
      }
    }
    if (j >= 28 && j < 56) {          // Y^T into regions; zero col-pads
      const int c = j - 28;
#pragma unroll
      for (int r2 = 0; r2 < 28; ++r2) {
        sm[wbA + c * 32 + r2] = colA[r2];
        sm[wbB + c * 32 + r2] = colB[r2];
      }
      *reinterpret_cast<float4*>(&sm[wbA + c * 32 + 28]) = z4;
      *reinterpret_cast<float4*>(&sm[wbB + c * 32 + 28]) = z4;
    }
    if (j >= 56) {                    // zero pad rows 28..31
      const int rr = 28 + ((j - 56) >> 1), half = (j - 56) & 1;
#pragma unroll
      for (int t = 0; t < 4; ++t) {
        *reinterpret_cast<float4*>(&sm[wbA + rr * 32 + half * 16 + 4 * t]) = z4;
        *reinterpret_cast<float4*>(&sm[wbB + rr * 32 + half * 16 + 4 * t]) = z4;
      }
    }
  }

  // ---- 6. Y fragments for both samples ----
  const P16 YA0 = splitpk16(*reinterpret_cast<const float4*>(&sm[wbA + li * 32 + 4 * gl]),
                            *reinterpret_cast<const float4*>(&sm[wbA + li * 32 + 16 + 4 * gl]));
  const P16 YA1 = splitpk16(*reinterpret_cast<const float4*>(&sm[wbA + (16 + li) * 32 + 4 * gl]),
                            *reinterpret_cast<const float4*>(&sm[wbA + (16 + li) * 32 + 16 + 4 * gl]));
  const P16 YB0 = splitpk16(*reinterpret_cast<const float4*>(&sm[wbB + li * 32 + 4 * gl]),
                            *reinterpret_cast<const float4*>(&sm[wbB + li * 32 + 16 + 4 * gl]));
  const P16 YB1 = splitpk16(*reinterpret_cast<const float4*>(&sm[wbB + (16 + li) * 32 + 4 * gl]),
                            *reinterpret_cast<const float4*>(&sm[wbB + (16 + li) * 32 + 16 + 4 * gl]));

  // ---- 7. B phase: W/bias shared; 2-term H per chain; direct stores ----
  float* BoA = Bout + (size_t)nA * 14336;
  float* BoB = Bout + (size_t)nB * 14336;
#pragma unroll 1
  for (int t = 0; t < 32; ++t) {
    const int T = (t + 8 * w) & 31;
    const int Tn = (t + 1 + 8 * w) & 31;
    const f16x8 Whi = __builtin_bit_cast(f16x8, pWh);
    const f16x8 Wlo = __builtin_bit_cast(f16x8, pWl);
    const float bv = pbv * NEG_LOG2E;
    pWh = wf[Tn * 64 + l];
    pWl = wf[(32 + Tn) * 64 + l];
    pbv = bias[16 * Tn + li];
    f32x4 aA0 = {bv, bv, bv, bv}, aA1 = aA0, aB0 = aA0, aB1 = aA0;
    aA0 = MFMA32(XA0.hi, Whi, aA0); aA0 = MFMA32(XA0.hi, Wlo, aA0);
    aA1 = MFMA32(XA1.hi, Whi, aA1); aA1 = MFMA32(XA1.hi, Wlo, aA1);
    aB0 = MFMA32(XB0.hi, Whi, aB0); aB0 = MFMA32(XB0.hi, Wlo, aB0);
    aB1 = MFMA32(XB1.hi, Whi, aB1); aB1 = MFMA32(XB1.hi, Wlo, aB1);
    float hvA[8], hvB[8];
#pragma unroll
    for (int i = 0; i < 4; ++i) {
      hvA[i] = sigm2(aA0[i]); hvA[4 + i] = sigm2(aA1[i]);
      hvB[i] = sigm2(aB0[i]); hvB[4 + i] = sigm2(aB1[i]);
    }
    const f16x8 BhA = pk8(hvA);
    const f16x8 BhB = pk8(hvB);
    f32x4 btA0 = {0,0,0,0}, btA1 = {0,0,0,0}, btB0 = {0,0,0,0}, btB1 = {0,0,0,0};
    btA0 = MFMA32(YA0.hi, BhA, btA0); btA0 = MFMA32(YA0.lo, BhA, btA0);
    btA1 = MFMA32(YA1.hi, BhA, btA1); btA1 = MFMA32(YA1.lo, BhA, btA1);
    btB0 = MFMA32(YB0.hi, BhB, btB0); btB0 = MFMA32(YB0.lo, BhB, btB0);
    btB1 = MFMA32(YB1.hi, BhB, btB1); btB1 = MFMA32(YB1.lo, BhB, btB1);
    float* BrA = BoA + (16 * T + li) * 28;
    float* BrB = BoB + (16 * T + li) * 28;
    *reinterpret_cast<float4*>(BrA + 4 * gl) = float4{btA0[0], btA0[1], btA0[2], btA0[3]};
    *reinterpret_cast<float4*>(BrB + 4 * gl) = float4{btB0[0], btB0[1], btB0[2], btB0[3]};
    if (gl < 3) {
      *reinterpret_cast<float4*>(BrA + 16 + 4 * gl) = float4{btA1[0], btA1[1], btA1[2], btA1[3]};
      *reinterpret_cast<float4*>(BrB + 16 + 4 * gl) = float4{btB1[0], btB1[1], btB1[2], btB1[3]};
    }
  }
}

extern "C" void kernel_launch(void* const* d_in, const int* in_sizes, int n_in,
                              void* d_out, int out_size, void* d_ws, size_t ws_size,
                              hipStream_t stream) {
  const float* x = (const float*)d_in[0];
  const float* W = (const float*)d_in[1];
  const float* b = (const float*)d_in[2];
  const int N = in_sizes[0] / 784;               // 4096 samples
  float* Xout = (float*)d_out;                   // [N,1,28,28]
  float* Bout = Xout + (size_t)N * 784;          // [N,1,512,28]
  uint4* wf = (uint4*)d_ws;                      // 65536 B
  f32x4* bfr = (f32x4*)((char*)d_ws + 65536);    // 32768 B
  prep_wfrag<<<8, 256, 0, stream>>>(W, b, wf, bfr);
  elm_kernel<<<N / 8, 256, 0, stream>>>(x, wf, bfr, b, Xout, Bout);
}

// Round 27
// 87.614 us; speedup vs baseline: 1.1058x; 1.1058x over previous
//
#include <hip/hip_runtime.h>

typedef _Float16 f16x8 __attribute__((ext_vector_type(8)));
typedef __fp16 hf2 __attribute__((ext_vector_type(2)));
typedef float f32x4 __attribute__((ext_vector_type(4)));

#define MFMA32(A, B, C) __builtin_amdgcn_mfma_f32_16x16x32_f16(A, B, C, 0, 0, 0)
#define NEG_LOG2E (-1.4426950408889634f)
#define PRIO1() __builtin_amdgcn_s_setprio(1)
#define PRIO0() __builtin_amdgcn_s_setprio(0)

extern "C" __device__ float __ocml_native_exp2_f32(float);  // v_exp_f32: 2^x

struct P16 { f16x8 hi, lo; };

// packed-pair f32->f16 conversion (1 op / 2 elems, pre-packed)
__device__ __forceinline__ f16x8 pk8(const float* v) {
  uint4 u;
  u.x = __builtin_bit_cast(unsigned, __builtin_amdgcn_cvt_pkrtz(v[0], v[1]));
  u.y = __builtin_bit_cast(unsigned, __builtin_amdgcn_cvt_pkrtz(v[2], v[3]));
  u.z = __builtin_bit_cast(unsigned, __builtin_amdgcn_cvt_pkrtz(v[4], v[5]));
  u.w = __builtin_bit_cast(unsigned, __builtin_amdgcn_cvt_pkrtz(v[6], v[7]));
  return __builtin_bit_cast(f16x8, u);
}
// hi/lo split via pkrtz: hi=RTZ(v), lo=RTZ(v-hi) (residual exact, 3-term ~2^-22)
__device__ __forceinline__ P16 splitpk(const float* v) {
  unsigned uh[4], ul[4];
  float lo[8];
#pragma unroll
  for (int e = 0; e < 4; ++e) {
    const hf2 h = __builtin_amdgcn_cvt_pkrtz(v[2 * e], v[2 * e + 1]);
    uh[e] = __builtin_bit_cast(unsigned, h);
    lo[2 * e]     = v[2 * e]     - (float)h[0];
    lo[2 * e + 1] = v[2 * e + 1] - (float)h[1];
  }
#pragma unroll
  for (int e = 0; e < 4; ++e)
    ul[e] = __builtin_bit_cast(unsigned, __builtin_amdgcn_cvt_pkrtz(lo[2 * e], lo[2 * e + 1]));
  P16 p;
  p.hi = __builtin_bit_cast(f16x8, uint4{uh[0], uh[1], uh[2], uh[3]});
  p.lo = __builtin_bit_cast(f16x8, uint4{ul[0], ul[1], ul[2], ul[3]});
  return p;
}
__device__ __forceinline__ P16 splitpk16(float4 a, float4 b) {
  float v[8] = {a.x, a.y, a.z, a.w, b.x, b.y, b.z, b.w};
  return splitpk(v);
}
// input already pre-scaled by -log2(e): h = 1/(1 + 2^a), native v_exp path
__device__ __forceinline__ float sigm2(float a) {
  return __builtin_amdgcn_rcpf(1.0f + __ocml_native_exp2_f32(a));
}

// prep: W' = -log2e * W [512][28] -> f16 hi/lo fragment planes wf[{0,1}*32+T][lane];
// element e: k = 4g+e (e<4) | 16+4g+(e-4), g=lane>>4; W-col = 16T + (lane&15).
// ALSO scaled bias fragments bf[(s*64+l)*2 + {0,1}] = -log2e * bias.
__global__ void prep_wfrag(const float* __restrict__ W, const float* __restrict__ bias,
                           uint4* __restrict__ wf, f32x4* __restrict__ bf) {
  const int id = blockIdx.x * 256 + threadIdx.x;
  if (id < 2048) {
    const int T = id >> 6, l = id & 63, g = (l >> 4) & 3, li = l & 15;
    const int col = 16 * T + li;
    unsigned hi[8], lo[8];
#pragma unroll
    for (int e = 0; e < 8; ++e) {
      const int k = (e < 4) ? (4 * g + e) : (16 + 4 * g + (e - 4));
      const float v = (k < 28) ? W[col * 28 + k] * NEG_LOG2E : 0.0f;
      const _Float16 h = (_Float16)v;
      const _Float16 lw = (_Float16)(v - (float)h);
      hi[e] = __builtin_bit_cast(unsigned short, h);
      lo[e] = __builtin_bit_cast(unsigned short, lw);
    }
    uint4 uh, ul;
    uh.x = hi[0] | (hi[1] << 16); uh.y = hi[2] | (hi[3] << 16);
    uh.z = hi[4] | (hi[5] << 16); uh.w = hi[6] | (hi[7] << 16);
    ul.x = lo[0] | (lo[1] << 16); ul.y = lo[2] | (lo[3] << 16);
    ul.z = lo[4] | (lo[5] << 16); ul.w = lo[6] | (lo[7] << 16);
    wf[T * 64 + l] = uh;
    wf[(32 + T) * 64 + l] = ul;
  }
  if (id < 1024) {
    const int s = id >> 6, l = id & 63, g = (l >> 4) & 3;
    f32x4 b0, b1;
#pragma unroll
    for (int e = 0; e < 4; ++e) {
      b0[e] = bias[32 * s + 4 * g + e] * NEG_LOG2E;
      b1[e] = bias[32 * s + 16 + 4 * g + e] * NEG_LOG2E;
    }
    bf[id * 2 + 0] = b0;
    bf[id * 2 + 1] = b1;
  }
}

// ONE WAVE = ONE SAMPLE (R25 base, 88.2us). R27: R25 verbatim + s_setprio(1)
// around the MFMA clusters (T5). Prereq per catalog: wave phase diversity --
// our waves are barrier-free and stagger-ordered (attn-like regime where T5
// gave +4-7%, m191), NOT the lockstep-GEMM regime where it was null (m190).
__global__ __launch_bounds__(256, 4) void elm_kernel(
    const float* __restrict__ x, const uint4* __restrict__ wf,
    const f32x4* __restrict__ bf, const float* __restrict__ bias,
    float* __restrict__ Xout, float* __restrict__ Bout)
{
  __shared__ __align__(16) float sm[4096];   // 4 x 1024-word wave regions
  const int tid = threadIdx.x;
  const int w = tid >> 6, l = tid & 63, gl = l >> 4, li = l & 15;
  const int n = blockIdx.x * 4 + w;
  const int wb = w * 1024;
  const float* xi = x + (size_t)n * 784;

  // ---- 1. x fragments (lane = x-row li / 16+li, elems = x-cols) ----
  const float4 z4 = {0, 0, 0, 0};
  const float4 xa0 = *reinterpret_cast<const float4*>(xi + li * 28 + 4 * gl);
  const float4 xb0 = (gl < 3) ? *reinterpret_cast<const float4*>(xi + li * 28 + 16 + 4 * gl) : z4;
  const int r1 = (li < 12) ? 16 + li : 0;
  float4 xa1 = *reinterpret_cast<const float4*>(xi + r1 * 28 + 4 * gl);
  float4 xb1 = (gl < 3) ? *reinterpret_cast<const float4*>(xi + r1 * 28 + 16 + 4 * gl) : z4;
  if (li >= 12) { xa1 = z4; xb1 = z4; }
  const P16 X0 = splitpk16(xa0, xb0);
  const P16 X1 = splitpk16(xa1, xb1);

  // ---- 2. G phase: 16 chunks of 32 h, wave-staggered, W prefetch depth 1,
  //         scaled bias pre-loaded into the MFMA C-operand ----
  f32x4 d00 = {0, 0, 0, 0}, d01 = {0, 0, 0, 0}, d11 = {0, 0, 0, 0};
  const int s_first = 4 * w;                    // (0 + 4w) & 15
  uint4 pW0h = wf[(2 * s_first) * 64 + l];
  uint4 pW0l = wf[(32 + 2 * s_first) * 64 + l];
  uint4 pW1h = wf[(2 * s_first + 1) * 64 + l];
  uint4 pW1l = wf[(32 + 2 * s_first + 1) * 64 + l];
#pragma unroll 2
  for (int ss = 0; ss < 16; ++ss) {
    const int s = (ss + 4 * w) & 15;            // wave-staggered chunk order
    const int sn = (ss + 1 + 4 * w) & 15;       // next chunk (last wraps, harmless)
    const f16x8 W0h = __builtin_bit_cast(f16x8, pW0h);
    const f16x8 W0l = __builtin_bit_cast(f16x8, pW0l);
    const f16x8 W1h = __builtin_bit_cast(f16x8, pW1h);
    const f16x8 W1l = __builtin_bit_cast(f16x8, pW1l);
    pW0h = wf[(2 * sn) * 64 + l];               // prefetch next chunk's W
    pW0l = wf[(32 + 2 * sn) * 64 + l];
    pW1h = wf[(2 * sn + 1) * 64 + l];
    pW1l = wf[(32 + 2 * sn + 1) * 64 + l];
    f32x4 P0 = bf[(s * 64 + l) * 2 + 0];        // scaled bias as C-init
    f32x4 Q0 = bf[(s * 64 + l) * 2 + 1];
    f32x4 P1 = P0, Q1 = Q0;
    PRIO1();
    P0 = MFMA32(W0h, X0.hi, P0); P0 = MFMA32(W0h, X0.lo, P0); P0 = MFMA32(W0l, X0.hi, P0);
    Q0 = MFMA32(W1h, X0.hi, Q0); Q0 = MFMA32(W1h, X0.lo, Q0); Q0 = MFMA32(W1l, X0.hi, Q0);
    P1 = MFMA32(W0h, X1.hi, P1); P1 = MFMA32(W0h, X1.lo, P1); P1 = MFMA32(W0l, X1.hi, P1);
    Q1 = MFMA32(W1h, X1.hi, Q1); Q1 = MFMA32(W1h, X1.lo, Q1); Q1 = MFMA32(W1l, X1.hi, Q1);
    PRIO0();
    float f0[8], f1[8];
#pragma unroll
    for (int i = 0; i < 4; ++i) {
      f0[i]     = sigm2(P0[i]);
      f0[4 + i] = sigm2(Q0[i]);
      f1[i]     = sigm2(P1[i]);
      f1[4 + i] = sigm2(Q1[i]);
    }
    const P16 F0 = splitpk(f0);
    const P16 F1 = splitpk(f1);
    PRIO1();
    d00 = MFMA32(F0.hi, F0.hi, d00); d00 = MFMA32(F0.hi, F0.lo, d00); d00 = MFMA32(F0.lo, F0.hi, d00);
    d01 = MFMA32(F0.hi, F1.hi, d01); d01 = MFMA32(F0.hi, F1.lo, d01); d01 = MFMA32(F0.lo, F1.hi, d01);
    d11 = MFMA32(F1.hi, F1.hi, d11); d11 = MFMA32(F1.hi, F1.lo, d11); d11 = MFMA32(F1.lo, F1.hi, d11);
    PRIO0();
  }

  // ---- 3. G fragments -> per-wave LDS Gc[r*32+c] (d01 mirrored = d10) ----
#pragma unroll
  for (int i = 0; i < 4; ++i) {
    const int ra = 4 * gl + i;
    sm[wb + ra * 32 + li] = d00[i];
    sm[wb + ra * 32 + 16 + li] = d01[i];
    sm[wb + (16 + li) * 32 + ra] = d01[i];
    sm[wb + (16 + ra) * 32 + 16 + li] = d11[i];
  }

  // ---- 4. X = x copy (stores overlap the solve) + B-phase prefetch ----
  {
    const float4* x4 = reinterpret_cast<const float4*>(xi);
    float4* X4 = reinterpret_cast<float4*>(Xout + (size_t)n * 784);
#pragma unroll
    for (int k = 0; k < 4; ++k) {
      const int idx = l + 64 * k;
      if (idx < 196) X4[idx] = x4[idx];
    }
  }
  uint4 pWh = wf[((8 * w) & 31) * 64 + l];      // B-phase prefetch: hidden by solve
  uint4 pWl = wf[(32 + ((8 * w) & 31)) * 64 + l];
  float pbv = bias[16 * ((8 * w) & 31) + li];

  // ---- 5. solve G Y = x : per-wave Gauss-Jordan; RHS from global x ----
  {
    const int j = l;
    float col[28];
#pragma unroll
    for (int r = 0; r < 28; ++r) {
      float v = 0.f;
      if (j < 28)      v = sm[wb + r * 32 + j];
      else if (j < 56) v = xi[r * 28 + (j - 28)];
      col[r] = v;
    }
#pragma unroll
    for (int k = 0; k < 28; ++k) {
      const float piv = __shfl(col[k], k);
      const float pivinv = 1.0f / piv;
      col[k] *= pivinv;
#pragma unroll
      for (int r2 = 0; r2 < 28; ++r2) {
        if (r2 == k) continue;
        const float m = __shfl(col[r2], k);
        col[r2] -= m * col[k];
      }
    }
    if (j >= 28 && j < 56) {          // Y^T: sm[c*32 + r]; zero col-pads
      const int c = j - 28;
#pragma unroll
      for (int r2 = 0; r2 < 28; ++r2) sm[wb + c * 32 + r2] = col[r2];
      *reinterpret_cast<float4*>(&sm[wb + c * 32 + 28]) = z4;
    }
    if (j >= 56) {                    // zero pad rows 28..31 (2 lanes/row)
      const int rr = 28 + ((j - 56) >> 1), half = (j - 56) & 1;
#pragma unroll
      for (int t = 0; t < 4; ++t)
        *reinterpret_cast<float4*>(&sm[wb + rr * 32 + half * 16 + 4 * t]) = z4;
    }
  }

  // ---- 6. Y A-fragments from per-wave Yt ----
  const P16 Y0 = splitpk16(*reinterpret_cast<const float4*>(&sm[wb + li * 32 + 4 * gl]),
                           *reinterpret_cast<const float4*>(&sm[wb + li * 32 + 16 + 4 * gl]));
  const P16 Y1 = splitpk16(*reinterpret_cast<const float4*>(&sm[wb + (16 + li) * 32 + 4 * gl]),
                           *reinterpret_cast<const float4*>(&sm[wb + (16 + li) * 32 + 16 + 4 * gl]));

  // ---- 7. B = H~^T Y : 2-term H recompute, depth-1 W+bias prefetch, staggered;
  //         scaled bias as C-init; no pad guards (Y zero at k>=28) ----
  float* Bo = Bout + (size_t)n * 14336;
#pragma unroll 2
  for (int t = 0; t < 32; ++t) {
    const int T = (t + 8 * w) & 31;             // wave-staggered tile order
    const int Tn = (t + 1 + 8 * w) & 31;        // next tile (wraps once, harmless)
    const f16x8 Whi = __builtin_bit_cast(f16x8, pWh);
    const f16x8 Wlo = __builtin_bit_cast(f16x8, pWl);
    const float bv = pbv * NEG_LOG2E;
    pWh = wf[Tn * 64 + l];                      // prefetch next tile's W + bias
    pWl = wf[(32 + Tn) * 64 + l];
    pbv = bias[16 * Tn + li];
    f32x4 a0 = {bv, bv, bv, bv}, a1 = {bv, bv, bv, bv};
    PRIO1();
    a0 = MFMA32(X0.hi, Whi, a0); a0 = MFMA32(X0.hi, Wlo, a0);   // 2-term
    a1 = MFMA32(X1.hi, Whi, a1); a1 = MFMA32(X1.hi, Wlo, a1);
    PRIO0();
    float hv[8];
#pragma unroll
    for (int i = 0; i < 4; ++i) {
      hv[i]     = sigm2(a0[i]);
      hv[4 + i] = sigm2(a1[i]);     // r>=28 garbage is multiplied by Y==0
    }
    const f16x8 Bhi = pk8(hv);
    f32x4 bt0 = {0, 0, 0, 0}, bt1 = {0, 0, 0, 0};
    PRIO1();
    bt0 = MFMA32(Y0.hi, Bhi, bt0); bt0 = MFMA32(Y0.lo, Bhi, bt0);
    bt1 = MFMA32(Y1.hi, Bhi, bt1); bt1 = MFMA32(Y1.lo, Bhi, bt1);
    PRIO0();
    float* Brow = Bo + (16 * T + li) * 28;
    *reinterpret_cast<float4*>(Brow + 4 * gl) = float4{bt0[0], bt0[1], bt0[2], bt0[3]};
    if (gl < 3)
      *reinterpret_cast<float4*>(Brow + 16 + 4 * gl) = float4{bt1[0], bt1[1], bt1[2], bt1[3]};
  }
}

extern "C" void kernel_launch(void* const* d_in, const int* in_sizes, int n_in,
                              void* d_out, int out_size, void* d_ws, size_t ws_size,
                              hipStream_t stream) {
  const float* x = (const float*)d_in[0];
  const float* W = (const float*)d_in[1];
  const float* b = (const float*)d_in[2];
  const int N = in_sizes[0] / 784;               // 4096 samples
  float* Xout = (float*)d_out;                   // [N,1,28,28]
  float* Bout = Xout + (size_t)N * 784;          // [N,1,512,28]
  uint4* wf = (uint4*)d_ws;                      // 65536 B
  f32x4* bfr = (f32x4*)((char*)d_ws + 65536);    // 32768 B
  prep_wfrag<<<8, 256, 0, stream>>>(W, b, wf, bfr);
  elm_kernel<<<N / 4, 256, 0, stream>>>(x, wf, bfr, b, Xout, Bout);
}